// Round 6
// baseline (129.223 us; speedup 1.0000x reference)
//
#include <hip/hip_runtime.h>
#include <stdint.h>

#define VOCAB 21128
#define NUMC  53
#define EMB   128
#define SEQ   512
#define BATCH 512

typedef __bf16 bf16x8 __attribute__((ext_vector_type(8)));
typedef float f32x4 __attribute__((ext_vector_type(4)));

__device__ __forceinline__ unsigned int f2bf1(float f) {
    union { float f; unsigned int u; } v; v.f = f;
    return (v.u + 0x7FFFu + ((v.u >> 16) & 1u)) >> 16;
}
__device__ __forceinline__ unsigned int pack2(float a, float b) {
    return f2bf1(a) | (f2bf1(b) << 16);
}

// Prep: emb fp32 -> bf16 Tb[VOCAB][128] (back from r5: bf16 table halves gather
// bytes vs direct-fp32-emb, which r5 measured as a 9 µs tile regression);
// conv_w -> Wp bf16 per-lane B-fragment order (16x16x32, verified r1-r10):
// Wp[s][g][lane][j] = w[f=g*16+(lane&15)][e=kk&127][tap=kk>>7], kk=s*32+(lane>>4)*8+j
__global__ void prep_kernel(const float* __restrict__ emb, const float* __restrict__ cw,
                            unsigned short* __restrict__ Tb, unsigned short* __restrict__ Wp) {
    int idx = blockIdx.x * blockDim.x + threadIdx.x;
    const int n8 = VOCAB * EMB / 8;  // 338048
    if (idx < n8) {
        const float4* src = (const float4*)emb + (size_t)idx * 2;
        float4 a = src[0], b = src[1];
        uint4 o;
        o.x = pack2(a.x, a.y);
        o.y = pack2(a.z, a.w);
        o.z = pack2(b.x, b.y);
        o.w = pack2(b.z, b.w);
        *(uint4*)(Tb + (size_t)idx * 8) = o;
    }
    if (idx < 12 * 8 * 64 * 8) {
        int j = idx & 7, l = (idx >> 3) & 63, g = (idx >> 9) & 7, s = idx >> 12;
        int kk = s * 32 + (l >> 4) * 8 + j;
        int f = g * 16 + (l & 15);
        int tap = kk >> 7, e = kk & 127;
        Wp[idx] = (unsigned short)f2bf1(cw[(f * EMB + e) * 3 + tap]);
    }
}

// 4096 blocks: block (b, tq) = batch row b, positions [tq*64, tq*64+64).
// 256 threads = 4 waves; wave wn owns filter group [wn*32,+32), M=64, acc[4][2].
//
// r5 post-mortem / staging redesign: r3's FETCH_SIZE = 135.7 MB matched
// (blocks x tasks) x 128 B EXACTLY -> each 16 B global_load_lds gather request
// fetches its own 128 B L2 line, no cross-lane merging => 8x read
// amplification (~550 MB/dispatch) on every DMA-gather variant. Fix: REG-STAGED
// gather (normal VMEM loads DO coalesce): 16 consecutive lanes read a
// CONTIGUOUS 256 B Tb row (linear chunk order -> 2x128 B txns per row), and
// the bank-conflict XOR swizzle moves to the LDS-WRITE side (ds_write_b128
// takes per-lane addresses; DMA's linear-dest restriction is gone). The
// MFMA-phase read path (slot (r, q^(r&15)) holds global chunk q) is unchanged.
__launch_bounds__(256, 5)
__global__ void pcnn_tile(const int* __restrict__ cid, const int* __restrict__ p1,
                          const int* __restrict__ p2,
                          const unsigned short* __restrict__ Tb,
                          const unsigned short* __restrict__ Wp,
                          float* __restrict__ Pd) {
    __shared__ __align__(16) unsigned short xs[66 * 128];  // 16,896 B

    const int bx   = blockIdx.x;
    const int b    = bx >> 3;
    const int tq   = bx & 7;
    const int tid  = threadIdx.x;
    const int lane = tid & 63;
    const int wn   = tid >> 6;   // 0..3 filter group (32 filters)
    const int quad = lane >> 4;
    const int lc   = lane & 15;

    const int* crow = cid + (size_t)b * SEQ;
    const char* TbB = (const char*)Tb;
    char* xsB = (char*)xs;

    // ---- Stage: 66 rows x 16 chunks = 1056 tasks; row r <-> pos tq*64 + r - 1.
    // OOB -> id 0 (Tb row 0 all zeros). Global side LINEAR (lane c reads chunk c
    // of its row -> full coalescing); LDS side swizzled: slot (r, c^(r&15)).
    // All 5 row-loads issued before any LDS write (software-pipelined).
    uint4 st[5];
    int   slot[5];
#pragma unroll
    for (int i = 0; i < 5; ++i) {
        int task = tid + 256 * i;
        if (i < 4 || tid < 32) {
            int r = task >> 4, c = task & 15;
            int p = tq * 64 + r - 1;
            unsigned int id = (p >= 0 && p < SEQ) ? (unsigned int)crow[p] : 0u;
            st[i]   = *(const uint4*)(TbB + (size_t)id * 256u + c * 16);
            slot[i] = (r * 16 + (c ^ (r & 15))) * 16;
        }
    }
#pragma unroll
    for (int i = 0; i < 5; ++i) {
        if (i < 4 || tid < 32)
            *(uint4*)(xsB + slot[i]) = st[i];
    }

    int e1 = min(p1[b], p2[b]);
    int e2 = max(p1[b], p2[b]);
    if (e1 == e2) e2 = min(e1 + 1, SEQ);
    const int e1m = max(e1, 1);

    __syncthreads();

    // ---- Conv via MFMA 16x16x32 bf16: M=64 (4 mt), N=32/wave (2 nt), K=384
    f32x4 acc[4][2];
#pragma unroll
    for (int mt = 0; mt < 4; ++mt)
#pragma unroll
        for (int nt = 0; nt < 2; ++nt)
            acc[mt][nt] = (f32x4){0.f, 0.f, 0.f, 0.f};

#pragma unroll
    for (int s = 0; s < 12; ++s) {
        const int tap = s >> 2;
        const int q   = (s & 3) * 4 + quad;             // global 16 B chunk wanted
        const int cs  = q ^ ((lc + tap) & 15);          // swizzled LDS chunk (= q^(r&15))
        bf16x8 b0 = *(const bf16x8*)(Wp + (size_t)((s * 8 + wn * 2) * 64 + lane) * 8);
        bf16x8 b1 = *(const bf16x8*)(Wp + (size_t)((s * 8 + wn * 2 + 1) * 64 + lane) * 8);
#pragma unroll
        for (int mt = 0; mt < 4; ++mt) {
            int r = mt * 16 + lc + tap;
            bf16x8 a = *(const bf16x8*)(xs + r * 128 + cs * 8);
            acc[mt][0] = __builtin_amdgcn_mfma_f32_16x16x32_bf16(a, b0, acc[mt][0], 0, 0, 0);
            acc[mt][1] = __builtin_amdgcn_mfma_f32_16x16x32_bf16(a, b1, acc[mt][1], 0, 0, 0);
        }
    }

    // ---- Piecewise max over this tile's 64 positions (raw conv; bias+relu in combine)
    float smax[3][2];
#pragma unroll
    for (int s3 = 0; s3 < 3; ++s3) { smax[s3][0] = -1e30f; smax[s3][1] = -1e30f; }

#pragma unroll
    for (int mt = 0; mt < 4; ++mt)
#pragma unroll
        for (int reg = 0; reg < 4; ++reg) {
            int p = tq * 64 + mt * 16 + quad * 4 + reg;
            float a0 = (p < e1m) ? 0.f : -2e30f;
            float a1 = (p >= e1 && p < e2) ? 0.f : -2e30f;
            float a2 = (p >= e2) ? 0.f : -2e30f;
#pragma unroll
            for (int nt = 0; nt < 2; ++nt) {
                float v = acc[mt][nt][reg];
                smax[0][nt] = fmaxf(smax[0][nt], v + a0);
                smax[1][nt] = fmaxf(smax[1][nt], v + a1);
                smax[2][nt] = fmaxf(smax[2][nt], v + a2);
            }
        }

    // Quad reduction in-register (butterfly over lanes ^16, ^32); lane<16
    // stores this block's partial directly.
#pragma unroll
    for (int s3 = 0; s3 < 3; ++s3)
#pragma unroll
        for (int nt = 0; nt < 2; ++nt) {
            float v = smax[s3][nt];
            v = fmaxf(v, __shfl_xor(v, 16));
            v = fmaxf(v, __shfl_xor(v, 32));
            smax[s3][nt] = v;
        }
    if (lane < 16) {
        float* pd = Pd + ((size_t)b * 8 + tq) * 384;
#pragma unroll
        for (int s3 = 0; s3 < 3; ++s3)
#pragma unroll
            for (int nt = 0; nt < 2; ++nt)
                pd[s3 * 128 + wn * 32 + nt * 16 + lc] = smax[s3][nt];
    }
}

// Combine: max over the 8 tile-partials, bias+ReLU, FC 384->53. One block per row.
__launch_bounds__(256)
__global__ void pcnn_combine(const float* __restrict__ Pd, const float* __restrict__ cb,
                             const float* __restrict__ fcw, const float* __restrict__ fcb,
                             float* __restrict__ out) {
    __shared__ float pooled[384];
    __shared__ float fcred[NUMC][4];
    const int b = blockIdx.x;
    const int tid = threadIdx.x;

    for (int j = tid; j < 384; j += 256) {
        const float* pp = Pd + (size_t)b * 8 * 384 + j;
        float m0 = fmaxf(pp[0 * 384], pp[1 * 384]);
        float m1 = fmaxf(pp[2 * 384], pp[3 * 384]);
        float m2 = fmaxf(pp[4 * 384], pp[5 * 384]);
        float m3 = fmaxf(pp[6 * 384], pp[7 * 384]);
        float m = fmaxf(fmaxf(m0, m1), fmaxf(m2, m3));
        pooled[j] = fmaxf(m + cb[j & 127], 0.f);
    }
    __syncthreads();

    if (tid < 212) {
        int c = tid >> 2, q = tid & 3;
        const float* wrow = fcw + (size_t)c * 384 + q * 96;
        const float* pp   = pooled + q * 96;
        float sum = 0.f;
#pragma unroll 8
        for (int i = 0; i < 96; ++i) sum += wrow[i] * pp[i];
        fcred[c][q] = sum;
    }
    __syncthreads();
    if (tid < NUMC)
        out[(size_t)b * NUMC + tid] =
            fcred[tid][0] + fcred[tid][1] + fcred[tid][2] + fcred[tid][3] + fcb[tid];
}

extern "C" void kernel_launch(void* const* d_in, const int* in_sizes, int n_in,
                              void* d_out, int out_size, void* d_ws, size_t ws_size,
                              hipStream_t stream) {
    const int*   cid = (const int*)d_in[0];
    const int*   p1  = (const int*)d_in[1];
    const int*   p2  = (const int*)d_in[2];
    const float* emb = (const float*)d_in[3];
    const float* cw  = (const float*)d_in[4];
    const float* cb  = (const float*)d_in[5];
    const float* fcw = (const float*)d_in[6];
    const float* fcb = (const float*)d_in[7];
    float* out = (float*)d_out;

    // ws: Tb bf16 [VOCAB*128] (5,408,768 B) | Wp bf16 [49152] (98,304 B)
    //   | Pd fp32 [512*8*384] (6,291,456 B)
    unsigned short* Tb = (unsigned short*)d_ws;
    unsigned short* Wp = (unsigned short*)((char*)d_ws + (size_t)VOCAB * EMB * 2);
    float*          Pd = (float*)((char*)d_ws + (size_t)VOCAB * EMB * 2 + 98304);

    const int n8 = VOCAB * EMB / 8;
    const int prep_threads = 256;
    const int prep_blocks  = (n8 + prep_threads - 1) / prep_threads;
    prep_kernel<<<prep_blocks, prep_threads, 0, stream>>>(emb, cw, Tb, Wp);
    pcnn_tile<<<BATCH * 8, 256, 0, stream>>>(cid, p1, p2, Tb, Wp, Pd);
    pcnn_combine<<<BATCH, 256, 0, stream>>>(Pd, cb, fcw, fcb, out);
}

// Round 7
// 128.766 us; speedup vs baseline: 1.0036x; 1.0036x over previous
//
#include <hip/hip_runtime.h>
#include <stdint.h>

#define VOCAB 21128
#define NUMC  53
#define EMB   128
#define SEQ   512
#define BATCH 512

typedef __bf16 bf16x8 __attribute__((ext_vector_type(8)));
typedef float f32x4 __attribute__((ext_vector_type(4)));

__device__ __forceinline__ unsigned int f2bf1(float f) {
    union { float f; unsigned int u; } v; v.f = f;
    return (v.u + 0x7FFFu + ((v.u >> 16) & 1u)) >> 16;
}
__device__ __forceinline__ unsigned int pack2(float a, float b) {
    return f2bf1(a) | (f2bf1(b) << 16);
}

// Prep: emb fp32 -> bf16 Tb[VOCAB][128]; conv_w -> Wp bf16 per-lane B-fragment
// order (16x16x32, verified r1-r10):
// Wp[s][g][lane][j] = w[f=g*16+(lane&15)][e=kk&127][tap=kk>>7], kk=s*32+(lane>>4)*8+j
__global__ void prep_kernel(const float* __restrict__ emb, const float* __restrict__ cw,
                            unsigned short* __restrict__ Tb, unsigned short* __restrict__ Wp) {
    int idx = blockIdx.x * blockDim.x + threadIdx.x;
    const int n8 = VOCAB * EMB / 8;  // 338048
    if (idx < n8) {
        const float4* src = (const float4*)emb + (size_t)idx * 2;
        float4 a = src[0], b = src[1];
        uint4 o;
        o.x = pack2(a.x, a.y);
        o.y = pack2(a.z, a.w);
        o.z = pack2(b.x, b.y);
        o.w = pack2(b.z, b.w);
        *(uint4*)(Tb + (size_t)idx * 8) = o;
    }
    if (idx < 12 * 8 * 64 * 8) {
        int j = idx & 7, l = (idx >> 3) & 63, g = (idx >> 9) & 7, s = idx >> 12;
        int kk = s * 32 + (l >> 4) * 8 + j;
        int f = g * 16 + (l & 15);
        int tap = kk >> 7, e = kk & 127;
        Wp[idx] = (unsigned short)f2bf1(cw[(f * EMB + e) * 3 + tap]);
    }
}

// 2048 blocks: block (b, th) = batch row b, positions [th*128, th*128+128),
// processed as TWO 64-position tiles with double-buffered LDS.
//
// r6 post-mortem synthesis: DMA-gather variants are MSHR-bound on 8x-amplified
// line fills (135 MB, ~3 TB/s plateau -> 42 µs); r6's coalesced reg-stage cut
// FETCH to 27 MB but exposed the serial load->ds_write->barrier->compute chain
// (47 µs, all pipes <30%). This kernel keeps the coalesced reg-stage AND hides
// its latency intra-block: tile1's global loads are issued right after the
// first barrier (fire-and-forget into regs, sched_barrier pins them above
// compute), consumed by ds_write only after tile0's compute. Barriers are raw
// s_barrier + lgkmcnt(0) ONLY — __syncthreads would emit vmcnt(0) and drain
// the prefetch (r2's fatal flaw). LDS 2x16.9 KB -> 4 blocks/CU.
// Staging layout (from r6): global side LINEAR (lane c reads chunk c of its
// 256 B Tb row -> full coalescing, 2 lines/row); LDS side XOR-swizzled
// (slot (r, c^(r&15)) holds chunk c), so the MFMA read path is conflict-free
// and byte-identical to r0-r6.
__launch_bounds__(256, 4)
__global__ void pcnn_tile(const int* __restrict__ cid, const int* __restrict__ p1,
                          const int* __restrict__ p2,
                          const unsigned short* __restrict__ Tb,
                          const unsigned short* __restrict__ Wp,
                          float* __restrict__ Pd) {
    __shared__ __align__(16) unsigned short xs[2][66 * 128];  // 33,792 B

    const int bx   = blockIdx.x;
    const int b    = bx >> 2;
    const int th   = bx & 3;
    const int tid  = threadIdx.x;
    const int lane = tid & 63;
    const int wn   = tid >> 6;   // 0..3 filter group (32 filters)
    const int quad = lane >> 4;
    const int lc   = lane & 15;

    const int* crow = cid + (size_t)b * SEQ;
    const char* TbB = (const char*)Tb;

    int e1 = min(p1[b], p2[b]);
    int e2 = max(p1[b], p2[b]);
    if (e1 == e2) e2 = min(e1 + 1, SEQ);
    const int e1m = max(e1, 1);

    // ---- Staging helpers: 66 rows x 16 chunks = 1056 tasks; row r <-> pos
    // th*128 + half*64 + r - 1; OOB -> id 0 (Tb row 0 all zeros).
    uint4 st[5];
    int   slot[5];
    auto LOAD = [&](int half) {
#pragma unroll
        for (int i = 0; i < 5; ++i) {
            int task = tid + 256 * i;
            if (i < 4 || tid < 32) {
                int r = task >> 4, c = task & 15;
                int p = th * 128 + half * 64 + r - 1;
                unsigned int id = (p >= 0 && p < SEQ) ? (unsigned int)crow[p] : 0u;
                st[i]   = *(const uint4*)(TbB + (size_t)id * 256u + c * 16);
                slot[i] = (r * 16 + (c ^ (r & 15))) * 16;
            }
        }
    };
    auto WRITE = [&](int buf) {
        char* dst = (char*)xs[buf];
#pragma unroll
        for (int i = 0; i < 5; ++i)
            if (i < 4 || tid < 32)
                *(uint4*)(dst + slot[i]) = st[i];
    };

    float smax[3][2];
#pragma unroll
    for (int s3 = 0; s3 < 3; ++s3) { smax[s3][0] = -1e30f; smax[s3][1] = -1e30f; }

    // Conv via MFMA 16x16x32 bf16 on one 64-pos tile (M=64: 4 mt; N=32/wave:
    // 2 nt; K=384), then fold piecewise max into running smax.
    auto COMPUTE = [&](const unsigned short* xsc, int pbase) {
        f32x4 acc[4][2];
#pragma unroll
        for (int mt = 0; mt < 4; ++mt)
#pragma unroll
            for (int nt = 0; nt < 2; ++nt)
                acc[mt][nt] = (f32x4){0.f, 0.f, 0.f, 0.f};

#pragma unroll
        for (int s = 0; s < 12; ++s) {
            const int tap = s >> 2;
            const int q   = (s & 3) * 4 + quad;         // global 16 B chunk wanted
            const int cs  = q ^ ((lc + tap) & 15);      // swizzled LDS chunk (= q^(r&15))
            bf16x8 b0 = *(const bf16x8*)(Wp + (size_t)((s * 8 + wn * 2) * 64 + lane) * 8);
            bf16x8 b1 = *(const bf16x8*)(Wp + (size_t)((s * 8 + wn * 2 + 1) * 64 + lane) * 8);
#pragma unroll
            for (int mt = 0; mt < 4; ++mt) {
                int r = mt * 16 + lc + tap;
                bf16x8 a = *(const bf16x8*)(xsc + r * 128 + cs * 8);
                acc[mt][0] = __builtin_amdgcn_mfma_f32_16x16x32_bf16(a, b0, acc[mt][0], 0, 0, 0);
                acc[mt][1] = __builtin_amdgcn_mfma_f32_16x16x32_bf16(a, b1, acc[mt][1], 0, 0, 0);
            }
        }

#pragma unroll
        for (int mt = 0; mt < 4; ++mt)
#pragma unroll
            for (int reg = 0; reg < 4; ++reg) {
                int p = pbase + mt * 16 + quad * 4 + reg;
                float a0 = (p < e1m) ? 0.f : -2e30f;
                float a1 = (p >= e1 && p < e2) ? 0.f : -2e30f;
                float a2 = (p >= e2) ? 0.f : -2e30f;
#pragma unroll
                for (int nt = 0; nt < 2; ++nt) {
                    float v = acc[mt][nt][reg];
                    smax[0][nt] = fmaxf(smax[0][nt], v + a0);
                    smax[1][nt] = fmaxf(smax[1][nt], v + a1);
                    smax[2][nt] = fmaxf(smax[2][nt], v + a2);
                }
            }
    };

    // ---- Pipeline: stage t0 | prefetch t1 under compute t0 | write t1 | compute t1
    LOAD(0);
    WRITE(0);  // compiler inserts the vmcnt waits for st[] data deps
    asm volatile("s_waitcnt lgkmcnt(0)" ::: "memory");
    __builtin_amdgcn_s_barrier();

    LOAD(1);   // fire-and-forget: latency hides under COMPUTE below
    __builtin_amdgcn_sched_barrier(0);  // pin the loads above the compute phase

    COMPUTE(xs[0], th * 128);

    WRITE(1);  // vmcnt waits on st[] happen here, after ~full compute overlap
    asm volatile("s_waitcnt lgkmcnt(0)" ::: "memory");
    __builtin_amdgcn_s_barrier();

    COMPUTE(xs[1], th * 128 + 64);

    // ---- Quad reduction in-register (butterfly over lanes ^16, ^32); lane<16
    // stores this block's partial (covers 128 positions) directly.
#pragma unroll
    for (int s3 = 0; s3 < 3; ++s3)
#pragma unroll
        for (int nt = 0; nt < 2; ++nt) {
            float v = smax[s3][nt];
            v = fmaxf(v, __shfl_xor(v, 16));
            v = fmaxf(v, __shfl_xor(v, 32));
            smax[s3][nt] = v;
        }
    if (lane < 16) {
        float* pd = Pd + ((size_t)b * 4 + th) * 384;
#pragma unroll
        for (int s3 = 0; s3 < 3; ++s3)
#pragma unroll
            for (int nt = 0; nt < 2; ++nt)
                pd[s3 * 128 + wn * 32 + nt * 16 + lc] = smax[s3][nt];
    }
}

// Combine: max over the 4 tile-partials, bias+ReLU, FC 384->53. One block per row.
__launch_bounds__(256)
__global__ void pcnn_combine(const float* __restrict__ Pd, const float* __restrict__ cb,
                             const float* __restrict__ fcw, const float* __restrict__ fcb,
                             float* __restrict__ out) {
    __shared__ float pooled[384];
    __shared__ float fcred[NUMC][4];
    const int b = blockIdx.x;
    const int tid = threadIdx.x;

    for (int j = tid; j < 384; j += 256) {
        const float* pp = Pd + (size_t)b * 4 * 384 + j;
        float m = fmaxf(fmaxf(pp[0], pp[384]), fmaxf(pp[768], pp[1152]));
        pooled[j] = fmaxf(m + cb[j & 127], 0.f);
    }
    __syncthreads();

    if (tid < 212) {
        int c = tid >> 2, q = tid & 3;
        const float* wrow = fcw + (size_t)c * 384 + q * 96;
        const float* pp   = pooled + q * 96;
        float sum = 0.f;
#pragma unroll 8
        for (int i = 0; i < 96; ++i) sum += wrow[i] * pp[i];
        fcred[c][q] = sum;
    }
    __syncthreads();
    if (tid < NUMC)
        out[(size_t)b * NUMC + tid] =
            fcred[tid][0] + fcred[tid][1] + fcred[tid][2] + fcred[tid][3] + fcb[tid];
}

extern "C" void kernel_launch(void* const* d_in, const int* in_sizes, int n_in,
                              void* d_out, int out_size, void* d_ws, size_t ws_size,
                              hipStream_t stream) {
    const int*   cid = (const int*)d_in[0];
    const int*   p1  = (const int*)d_in[1];
    const int*   p2  = (const int*)d_in[2];
    const float* emb = (const float*)d_in[3];
    const float* cw  = (const float*)d_in[4];
    const float* cb  = (const float*)d_in[5];
    const float* fcw = (const float*)d_in[6];
    const float* fcb = (const float*)d_in[7];
    float* out = (float*)d_out;

    // ws: Tb bf16 [VOCAB*128] (5,408,768 B) | Wp bf16 [49152] (98,304 B)
    //   | Pd fp32 [512*4*384] (3,145,728 B)
    unsigned short* Tb = (unsigned short*)d_ws;
    unsigned short* Wp = (unsigned short*)((char*)d_ws + (size_t)VOCAB * EMB * 2);
    float*          Pd = (float*)((char*)d_ws + (size_t)VOCAB * EMB * 2 + 98304);

    const int n8 = VOCAB * EMB / 8;
    const int prep_threads = 256;
    const int prep_blocks  = (n8 + prep_threads - 1) / prep_threads;
    prep_kernel<<<prep_blocks, prep_threads, 0, stream>>>(emb, cw, Tb, Wp);
    pcnn_tile<<<BATCH * 4, 256, 0, stream>>>(cid, p1, p2, Tb, Wp, Pd);
    pcnn_combine<<<BATCH, 256, 0, stream>>>(Pd, cb, fcw, fcb, out);
}

// Round 8
// 114.243 us; speedup vs baseline: 1.1311x; 1.1271x over previous
//
#include <hip/hip_runtime.h>
#include <stdint.h>

#define VOCAB 21128
#define NUMC  53
#define EMB   128
#define SEQ   512
#define BATCH 512

typedef __bf16 bf16x8 __attribute__((ext_vector_type(8)));
typedef float f32x4 __attribute__((ext_vector_type(4)));
typedef __attribute__((address_space(3))) void lds_void;
typedef const __attribute__((address_space(1))) void glob_void;

__device__ __forceinline__ unsigned int f2bf1(float f) {
    union { float f; unsigned int u; } v; v.f = f;
    return (v.u + 0x7FFFu + ((v.u >> 16) & 1u)) >> 16;
}
__device__ __forceinline__ unsigned int pack2(float a, float b) {
    return f2bf1(a) | (f2bf1(b) << 16);
}

// Prep: emb_table fp32 -> bf16 Tb[VOCAB][128] (8 elem/thread, vectorized);
// conv_w -> Wp bf16 in per-lane B-fragment order (16x16x32, verified r1-r10):
// Wp[s 0..11][g 0..7][lane 0..63][j 0..7] = w[f=g*16+(lane&15)][e=kk&127][tap=kk>>7],
// kk = s*32 + (lane>>4)*8 + j
__global__ void prep_kernel(const float* __restrict__ emb, const float* __restrict__ cw,
                            unsigned short* __restrict__ Tb, unsigned short* __restrict__ Wp) {
    int idx = blockIdx.x * blockDim.x + threadIdx.x;
    const int n8 = VOCAB * EMB / 8;  // 338048
    if (idx < n8) {
        const float4* src = (const float4*)emb + (size_t)idx * 2;
        float4 a = src[0], b = src[1];
        uint4 o;
        o.x = pack2(a.x, a.y);
        o.y = pack2(a.z, a.w);
        o.z = pack2(b.x, b.y);
        o.w = pack2(b.z, b.w);
        *(uint4*)(Tb + (size_t)idx * 8) = o;
    }
    if (idx < 12 * 8 * 64 * 8) {
        int j = idx & 7, l = (idx >> 3) & 63, g = (idx >> 9) & 7, s = idx >> 12;
        int kk = s * 32 + (l >> 4) * 8 + j;
        int f = g * 16 + (l & 15);
        int tap = kk >> 7, e = kk & 127;
        Wp[idx] = (unsigned short)f2bf1(cw[(f * EMB + e) * 3 + tap]);
    }
}

// 2048 blocks: block (b, tq) = batch row b, positions [tq*128, tq*128+128).
// 512 threads = 8 waves; wave w: wm=w&1 (64-pos half), wn=w>>1 (32-filter group).
// This is the best-measured structure (114.33 µs) + ONE surgical fix:
//
// LINE-WARMING PASS (r7 post-mortem): r3's FETCH_SIZE = 128 B x #DMA-tasks
// exactly => same-line global_load_lds requests do NOT MSHR-merge; the 8
// outstanding 16-B requests per 128-B line each fetch the line from HBM
// (8x amplification, ~550 MB equiv; r0's tile ran at the ~4.8 TB/s mixed
// plateau => HBM-throughput-bound). Fix: before the DMA stage, threads 0-259
// each issue ONE dword load to a distinct line of the block's 260 Tb lines
// (normal VMEM path, distinct lines -> clean unamplified fills), then
// __syncthreads (vmcnt(0) is desired: nothing else is in flight). The DMA
// stage below then finds every line L2-hot — its non-merging requests become
// L2 hits instead of 8x HBM fetches.
//
// Staging via global_load_lds (16 B DMA, per-lane gather addr, wave-uniform LDS
// dest = base + lane*16): zero VGPR round-trip, zero pack VALU. LDS rows are
// UNPADDED 256 B (DMA requires contiguity); bank conflicts broken by an XOR
// swizzle within each row: LDS slot (r,c) holds global chunk c^(r&15).
// B fragments loaded IN-LOOP from L2-hot Wp (r11: preloading costs occupancy).
__launch_bounds__(512)
__global__ void pcnn_tile(const int* __restrict__ cid, const int* __restrict__ p1,
                          const int* __restrict__ p2,
                          const unsigned short* __restrict__ Tb,
                          const unsigned short* __restrict__ Wp,
                          float* __restrict__ Pd) {
    __shared__ __align__(16) unsigned short xs[130 * 128];  // 33,280 B, unpadded
    __shared__ float pstage[2][3][128];                     // 3,072 B

    const int bx   = blockIdx.x;
    const int b    = bx >> 2;
    const int tq   = bx & 3;
    const int tid  = threadIdx.x;
    const int lane = tid & 63;
    const int w    = tid >> 6;
    const int wm   = w & 1;
    const int wn   = w >> 1;
    const int quad = lane >> 4;
    const int lc   = lane & 15;

    const int* crow = cid + (size_t)b * SEQ;
    const char* TbB = (const char*)Tb;
    char* xsB = (char*)xs;

    // ---- Pass A: open each of the block's 260 Tb lines once (coalesced dword
    // per line, all lines distinct -> no MSHR same-line pileup). asm sink keeps
    // the loads live (rule #17). The __syncthreads drains them into L2.
    if (tid < 260) {
        int r = tid >> 1, h = tid & 1;
        int p = tq * 128 + r - 1;
        unsigned int id = (p >= 0 && p < SEQ) ? (unsigned int)crow[p] : 0u;
        unsigned int warm = *(const unsigned int*)(TbB + (size_t)id * 256u + h * 128);
        asm volatile("" :: "v"(warm));
    }
    __syncthreads();  // vmcnt(0)+barrier: warm fills complete before DMA issue

    // ---- Stage: 130 rows x 16 chunks = 2080 tasks; row r <-> pos tq*128 + r - 1.
    // OOB -> id 0 (Tb row 0 all zeros). Lane loads global chunk (c ^ (r&15)) of
    // its row; DMA places it at LDS slot task*16 (= base + lane*16 within a wave).
#pragma unroll
    for (int i = 0; i < 5; ++i) {
        int task = tid + 512 * i;
        if (task < 2080) {
            int r = task >> 4, c = task & 15;
            int p = tq * 128 + r - 1;
            unsigned int id = (p >= 0 && p < SEQ) ? (unsigned int)crow[p] : 0u;
            int cs = c ^ (r & 15);
            __builtin_amdgcn_global_load_lds(
                (glob_void*)(TbB + (size_t)id * 256u + cs * 16),
                (lds_void*)(xsB + task * 16), 16, 0, 0);
        }
    }

    int e1 = min(p1[b], p2[b]);
    int e2 = max(p1[b], p2[b]);
    if (e1 == e2) e2 = min(e1 + 1, SEQ);
    const int e1m = max(e1, 1);

    __syncthreads();  // full vmcnt drain + barrier

    // ---- Conv via MFMA 16x16x32 bf16: M=128 (wm half x 4 mt), N=32/wave (2 nt), K=384
    f32x4 acc[4][2];
#pragma unroll
    for (int mt = 0; mt < 4; ++mt)
#pragma unroll
        for (int nt = 0; nt < 2; ++nt)
            acc[mt][nt] = (f32x4){0.f, 0.f, 0.f, 0.f};

#pragma unroll
    for (int s = 0; s < 12; ++s) {
        const int tap = s >> 2;
        const int q   = (s & 3) * 4 + quad;             // global 16 B chunk wanted
        const int cs  = q ^ ((lc + tap) & 15);          // swizzled LDS chunk (= q^(r&15))
        bf16x8 b0 = *(const bf16x8*)(Wp + (size_t)((s * 8 + wn * 2) * 64 + lane) * 8);
        bf16x8 b1 = *(const bf16x8*)(Wp + (size_t)((s * 8 + wn * 2 + 1) * 64 + lane) * 8);
        bf16x8 af[4];
#pragma unroll
        for (int mt = 0; mt < 4; ++mt) {
            int r = wm * 64 + mt * 16 + lc + tap;
            af[mt] = *(const bf16x8*)(xs + r * 128 + cs * 8);
        }
#pragma unroll
        for (int mt = 0; mt < 4; ++mt) {
            acc[mt][0] = __builtin_amdgcn_mfma_f32_16x16x32_bf16(af[mt], b0, acc[mt][0], 0, 0, 0);
            acc[mt][1] = __builtin_amdgcn_mfma_f32_16x16x32_bf16(af[mt], b1, acc[mt][1], 0, 0, 0);
        }
    }

    // ---- Piecewise max over this tile's 128 positions (raw conv; bias+relu in combine)
    float smax[3][2];
#pragma unroll
    for (int s3 = 0; s3 < 3; ++s3) { smax[s3][0] = -1e30f; smax[s3][1] = -1e30f; }

#pragma unroll
    for (int mt = 0; mt < 4; ++mt)
#pragma unroll
        for (int reg = 0; reg < 4; ++reg) {
            int p = tq * 128 + wm * 64 + mt * 16 + quad * 4 + reg;
            float a0 = (p < e1m) ? 0.f : -2e30f;
            float a1 = (p >= e1 && p < e2) ? 0.f : -2e30f;
            float a2 = (p >= e2) ? 0.f : -2e30f;
#pragma unroll
            for (int nt = 0; nt < 2; ++nt) {
                float v = acc[mt][nt][reg];
                smax[0][nt] = fmaxf(smax[0][nt], v + a0);
                smax[1][nt] = fmaxf(smax[1][nt], v + a1);
                smax[2][nt] = fmaxf(smax[2][nt], v + a2);
            }
        }

    // Quad reduction in-register (butterfly over lanes ^16, ^32)
#pragma unroll
    for (int s3 = 0; s3 < 3; ++s3)
#pragma unroll
        for (int nt = 0; nt < 2; ++nt) {
            float v = smax[s3][nt];
            v = fmaxf(v, __shfl_xor(v, 16));
            v = fmaxf(v, __shfl_xor(v, 32));
            smax[s3][nt] = v;
        }
    if (lane < 16) {
#pragma unroll
        for (int s3 = 0; s3 < 3; ++s3)
#pragma unroll
            for (int nt = 0; nt < 2; ++nt)
                pstage[wm][s3][(wn * 2 + nt) * 16 + lc] = smax[s3][nt];
    }
    __syncthreads();

    if (tid < 384) {
        int s3 = tid >> 7, f = tid & 127;
        Pd[((size_t)b * 4 + tq) * 384 + tid] = fmaxf(pstage[0][s3][f], pstage[1][s3][f]);
    }
}

// Combine: max over the 4 tile-partials, bias+ReLU, FC 384->53. One block per row.
__launch_bounds__(256)
__global__ void pcnn_combine(const float* __restrict__ Pd, const float* __restrict__ cb,
                             const float* __restrict__ fcw, const float* __restrict__ fcb,
                             float* __restrict__ out) {
    __shared__ float pooled[384];
    __shared__ float fcred[NUMC][4];
    const int b = blockIdx.x;
    const int tid = threadIdx.x;

    for (int j = tid; j < 384; j += 256) {
        const float* pp = Pd + (size_t)b * 4 * 384 + j;
        float m = fmaxf(fmaxf(pp[0], pp[384]), fmaxf(pp[768], pp[1152]));
        pooled[j] = fmaxf(m + cb[j & 127], 0.f);
    }
    __syncthreads();

    if (tid < 212) {
        int c = tid >> 2, q = tid & 3;
        const float* wrow = fcw + (size_t)c * 384 + q * 96;
        const float* pp   = pooled + q * 96;
        float sum = 0.f;
#pragma unroll 8
        for (int i = 0; i < 96; ++i) sum += wrow[i] * pp[i];
        fcred[c][q] = sum;
    }
    __syncthreads();
    if (tid < NUMC)
        out[(size_t)b * NUMC + tid] =
            fcred[tid][0] + fcred[tid][1] + fcred[tid][2] + fcred[tid][3] + fcb[tid];
}

extern "C" void kernel_launch(void* const* d_in, const int* in_sizes, int n_in,
                              void* d_out, int out_size, void* d_ws, size_t ws_size,
                              hipStream_t stream) {
    const int*   cid = (const int*)d_in[0];
    const int*   p1  = (const int*)d_in[1];
    const int*   p2  = (const int*)d_in[2];
    const float* emb = (const float*)d_in[3];
    const float* cw  = (const float*)d_in[4];
    const float* cb  = (const float*)d_in[5];
    const float* fcw = (const float*)d_in[6];
    const float* fcb = (const float*)d_in[7];
    float* out = (float*)d_out;

    // ws: Tb bf16 [VOCAB*128] (5,408,768 B) | Wp bf16 [49152] (98,304 B)
    //   | Pd fp32 [512*4*384] (3,145,728 B)
    unsigned short* Tb = (unsigned short*)d_ws;
    unsigned short* Wp = (unsigned short*)((char*)d_ws + (size_t)VOCAB * EMB * 2);
    float*          Pd = (float*)((char*)d_ws + (size_t)VOCAB * EMB * 2 + 98304);

    const int n8 = VOCAB * EMB / 8;
    const int prep_threads = 256;
    const int prep_blocks  = (n8 + prep_threads - 1) / prep_threads;
    prep_kernel<<<prep_blocks, prep_threads, 0, stream>>>(emb, cw, Tb, Wp);
    pcnn_tile<<<BATCH * 4, 512, 0, stream>>>(cid, p1, p2, Tb, Wp, Pd);
    pcnn_combine<<<BATCH, 256, 0, stream>>>(Pd, cb, fcw, fcb, out);
}